// Round 1
// 369.530 us; speedup vs baseline: 1.0312x; 1.0312x over previous
//
#include <hip/hip_runtime.h>
#include <cstdint>
#include <cstring>
#include <cmath>
#include <cfloat>

// Switch if harness JAX uses pre-partitionable threefry (would show absmax ~500)
#ifndef THREEFRY_PARTITIONABLE
#define THREEFRY_PARTITIONABLE 1
#endif

#define B_FIXED 16
#define PB 128   // reduction blocks per sample

struct SampleRand {
  float flipsign;      // -1 if flip else +1
  float c, s;          // cos/sin of rotation angle
  float sx, sy, sz;    // shift
  float r1x, r1y, r1z;
  float r2x, r2y, r2z;
};
struct AllRand { SampleRand r[B_FIXED]; };

// ---------------- host-side JAX-exact RNG ----------------
static inline void tf2x32(uint32_t k0, uint32_t k1, uint32_t x0, uint32_t x1,
                          uint32_t& o0, uint32_t& o1) {
  const uint32_t ks[3] = {k0, k1, k0 ^ k1 ^ 0x1BD11BDAu};
  static const uint32_t R[2][4] = {{13u,15u,26u,6u},{17u,29u,16u,24u}};
  x0 += ks[0]; x1 += ks[1];
  for (int i = 0; i < 5; ++i) {
    const uint32_t* r = R[i & 1];
    for (int j = 0; j < 4; ++j) {
      x0 += x1;
      x1 = (x1 << r[j]) | (x1 >> (32u - r[j]));
      x1 ^= x0;
    }
    x0 += ks[(i + 1) % 3];
    x1 += ks[(i + 2) % 3] + (uint32_t)(i + 1);
  }
  o0 = x0; o1 = x1;
}

static inline float u01_from_bits(uint32_t bits) {
  uint32_t fb = (bits >> 9) | 0x3f800000u;
  float f; memcpy(&f, &fb, 4);
  return f - 1.0f;   // in [0,1)
}

static inline uint32_t bits_scalar(uint32_t k0, uint32_t k1) {
  uint32_t a, b; tf2x32(k0, k1, 0u, 0u, a, b);
#if THREEFRY_PARTITIONABLE
  return a ^ b;
#else
  return a;
#endif
}

static inline void bits_vec3(uint32_t k0, uint32_t k1, uint32_t out[3]) {
#if THREEFRY_PARTITIONABLE
  for (uint32_t i = 0; i < 3; ++i) { uint32_t a, b; tf2x32(k0, k1, 0u, i, a, b); out[i] = a ^ b; }
#else
  uint32_t a0,b0,a1,b1;
  tf2x32(k0, k1, 0u, 2u, a0, b0);
  tf2x32(k0, k1, 1u, 0u, a1, b1);
  out[0] = a0; out[1] = a1; out[2] = b0;
#endif
}

static float erfinv32(float x) {   // XLA ErfInv32 (Giles)
#pragma clang fp contract(off)
  float w = -log1pf(-x * x);
  float p;
  if (w < 5.0f) {
    w = w - 2.5f;
    p = 2.81022636e-08f;
    p = 3.43273939e-07f + p * w;
    p = -3.5233877e-06f + p * w;
    p = -4.39150654e-06f + p * w;
    p = 0.00021858087f + p * w;
    p = -0.00125372503f + p * w;
    p = -0.00417768164f + p * w;
    p = 0.246640727f + p * w;
    p = 1.50140941f + p * w;
  } else {
    w = sqrtf(w) - 3.0f;
    p = -0.000200214257f;
    p = 0.000100950558f + p * w;
    p = 0.00134934322f + p * w;
    p = -0.00367342844f + p * w;
    p = 0.00573950773f + p * w;
    p = -0.0076224613f + p * w;
    p = 0.00943887047f + p * w;
    p = 1.00167406f + p * w;
    p = 2.83297682f + p * w;
  }
  return p * x;
}

static void fill_rand(AllRand& ar) {
#pragma clang fp contract(off)
  const int num = B_FIXED * 5;
  uint32_t keys[B_FIXED * 5][2];
#if THREEFRY_PARTITIONABLE
  for (int j = 0; j < num; ++j)
    tf2x32(0u, 42u, 0u, (uint32_t)j, keys[j][0], keys[j][1]);
#else
  // original split: flat = concat(E(i,i+num).a for i<num, E(i,i+num).b for i<num)
  for (int j = 0; j < num; ++j) {
    uint32_t a, b;
    int i0 = 2 * j, i1 = 2 * j + 1;
    if (i0 < num) { tf2x32(0u, 42u, (uint32_t)i0, (uint32_t)(i0 + num), a, b); keys[j][0] = a; }
    else          { tf2x32(0u, 42u, (uint32_t)(i0 - num), (uint32_t)i0, a, b); keys[j][0] = b; }
    if (i1 < num) { tf2x32(0u, 42u, (uint32_t)i1, (uint32_t)(i1 + num), a, b); keys[j][1] = a; }
    else          { tf2x32(0u, 42u, (uint32_t)(i1 - num), (uint32_t)i1, a, b); keys[j][1] = b; }
  }
#endif
  const float varr[3] = {0.1f, 0.1f, 0.05f};
  const float LO = -0.99999994f;          // nextafter(-1, 0) in f32
  const float SQRT2 = 0x1.6a09e6p+0f;     // float32(sqrt(2))
  for (int b = 0; b < B_FIXED; ++b) {
    const uint32_t* kf = keys[5 * b + 0];
    const uint32_t* kr = keys[5 * b + 1];
    const uint32_t* ks = keys[5 * b + 2];
    const uint32_t* k1 = keys[5 * b + 3];
    const uint32_t* k2 = keys[5 * b + 4];
    float uflip = u01_from_bits(bits_scalar(kf[0], kf[1]));
    ar.r[b].flipsign = (uflip < 0.25f) ? -1.0f : 1.0f;
    float urot = u01_from_bits(bits_scalar(kr[0], kr[1]));
    float ang = urot - 0.5f;
    ang = ang * (float)(30.0 / 180.0);
    ang = ang * (float)3.14159265358979323846;
    ar.r[b].c = (float)cos((double)ang);
    ar.r[b].s = (float)sin((double)ang);
    uint32_t bs[3]; bits_vec3(ks[0], ks[1], bs);
    float sh[3];
    for (int i = 0; i < 3; ++i) {
      float f = u01_from_bits(bs[i]);
      float v = f * 2.0f + LO;     // f*2 exact; matches fl(f*(hi-lo)+lo), hi-lo rounds to 2.0f
      v = fmaxf(LO, v);
      float n = SQRT2 * erfinv32(v);
      sh[i] = n * varr[i];
    }
    ar.r[b].sx = sh[0]; ar.r[b].sy = sh[1]; ar.r[b].sz = sh[2];
    uint32_t b1[3], b2[3];
    bits_vec3(k1[0], k1[1], b1);
    bits_vec3(k2[0], k2[1], b2);
    ar.r[b].r1x = u01_from_bits(b1[0]); ar.r[b].r1y = u01_from_bits(b1[1]); ar.r[b].r1z = u01_from_bits(b1[2]);
    ar.r[b].r2x = u01_from_bits(b2[0]); ar.r[b].r2y = u01_from_bits(b2[1]); ar.r[b].r2z = u01_from_bits(b2[2]);
  }
}

// ---------------- device helpers ----------------
__device__ __forceinline__ double wredd(double v) {
  for (int o = 32; o > 0; o >>= 1) v += __shfl_down(v, o);
  return v;
}
__device__ __forceinline__ float wredmin(float v) {
  for (int o = 32; o > 0; o >>= 1) v = fminf(v, __shfl_down(v, o));
  return v;
}
__device__ __forceinline__ float wredmax(float v) {
  for (int o = 32; o > 0; o >>= 1) v = fmaxf(v, __shfl_down(v, o));
  return v;
}

// Kernel A: per-sample partial reductions (sum, sumsq over 4 cols; min/max of a over 3 cols)
__global__ __launch_bounds__(256)
void k_reduce(const float4* __restrict__ pts, int N, const int* __restrict__ scale_p,
              AllRand ar, double* __restrict__ psum, float* __restrict__ pmm) {
  const int b = blockIdx.y, p = blockIdx.x, t = threadIdx.x;
  const SampleRand R = ar.r[b];
  const float sc = (float)(*scale_p);
  const float4* base = pts + (size_t)b * N;
  double s0 = 0, s1 = 0, s2 = 0, s3 = 0, q0 = 0, q1 = 0, q2 = 0, q3 = 0;
  float mn0 = FLT_MAX, mn1 = FLT_MAX, mn2 = FLT_MAX;
  float mx0 = -FLT_MAX, mx1 = -FLT_MAX, mx2 = -FLT_MAX;
  const int stride = gridDim.x * blockDim.x;
  for (int i = p * 256 + t; i < N; i += stride) {
    float4 P = base[i];
    float y = R.flipsign * P.y;
    float xr = __fsub_rn(__fmul_rn(P.x, R.c), __fmul_rn(y, R.s));
    float yr = __fadd_rn(__fmul_rn(P.x, R.s), __fmul_rn(y, R.c));
    float X = __fadd_rn(xr, R.sx), Y = __fadd_rn(yr, R.sy), Z = __fadd_rn(P.z, R.sz), W = P.w;
    s0 += X; s1 += Y; s2 += Z; s3 += W;
    q0 += (double)X * (double)X; q1 += (double)Y * (double)Y;
    q2 += (double)Z * (double)Z; q3 += (double)W * (double)W;
    float a0 = __fmul_rn(sc, X), a1 = __fmul_rn(sc, Y), a2 = __fmul_rn(sc, Z);
    mn0 = fminf(mn0, a0); mx0 = fmaxf(mx0, a0);
    mn1 = fminf(mn1, a1); mx1 = fmaxf(mx1, a1);
    mn2 = fminf(mn2, a2); mx2 = fmaxf(mx2, a2);
  }
  __shared__ double sd[4][8];
  __shared__ float  sf[4][6];
  const int w = t >> 6, l = t & 63;
  double r0 = wredd(s0), r1 = wredd(s1), r2 = wredd(s2), r3 = wredd(s3);
  double r4 = wredd(q0), r5 = wredd(q1), r6 = wredd(q2), r7 = wredd(q3);
  float f0 = wredmin(mn0), f1 = wredmin(mn1), f2 = wredmin(mn2);
  float f3 = wredmax(mx0), f4 = wredmax(mx1), f5 = wredmax(mx2);
  if (l == 0) {
    sd[w][0] = r0; sd[w][1] = r1; sd[w][2] = r2; sd[w][3] = r3;
    sd[w][4] = r4; sd[w][5] = r5; sd[w][6] = r6; sd[w][7] = r7;
    sf[w][0] = f0; sf[w][1] = f1; sf[w][2] = f2;
    sf[w][3] = f3; sf[w][4] = f4; sf[w][5] = f5;
  }
  __syncthreads();
  if (t == 0) {
    const size_t idx = (size_t)b * PB + p;
    double* op = psum + idx * 8;
    for (int c = 0; c < 8; ++c) op[c] = sd[0][c] + sd[1][c] + sd[2][c] + sd[3][c];
    float* om = pmm + idx * 6;
    for (int c = 0; c < 3; ++c) om[c] = fminf(fminf(sf[0][c], sf[1][c]), fminf(sf[2][c], sf[3][c]));
    for (int c = 3; c < 6; ++c) om[c] = fmaxf(fmaxf(sf[0][c], sf[1][c]), fmaxf(sf[2][c], sf[3][c]));
  }
}

// Kernel B: finalize mean/std/offset per sample; write offsets output
__global__ __launch_bounds__(PB)
void k_params(const double* __restrict__ psum, const float* __restrict__ pmm,
              int N, const float* __restrict__ fs, AllRand ar,
              float* __restrict__ params, float* __restrict__ out_off) {
  const int b = blockIdx.x, t = threadIdx.x;
  const size_t idx = (size_t)b * PB + t;
  double s[8]; float mm[6];
  for (int c = 0; c < 8; ++c) s[c] = psum[idx * 8 + c];
  for (int c = 0; c < 6; ++c) mm[c] = pmm[idx * 6 + c];
  for (int c = 0; c < 8; ++c) s[c] = wredd(s[c]);
  for (int c = 0; c < 3; ++c) mm[c] = wredmin(mm[c]);
  for (int c = 3; c < 6; ++c) mm[c] = wredmax(mm[c]);
  __shared__ double sd[2][8];
  __shared__ float  sf[2][6];
  const int w = t >> 6, l = t & 63;
  if (l == 0) {
    for (int c = 0; c < 8; ++c) sd[w][c] = s[c];
    for (int c = 0; c < 6; ++c) sf[w][c] = mm[c];
  }
  __syncthreads();
  if (t == 0) {
    const SampleRand R = ar.r[b];
    const float r1v[3] = {R.r1x, R.r1y, R.r1z};
    const float r2v[3] = {R.r2x, R.r2y, R.r2z};
    float* pp = params + b * 12;
    const double Nd = (double)N;
    for (int c = 0; c < 4; ++c) {
      double su = sd[0][c] + sd[1][c];
      double sq = sd[0][c + 4] + sd[1][c + 4];
      double mean = su / Nd;
      double var = (sq - su * su / Nd) / (Nd - 1.0);
      if (var < 0.0) var = 0.0;
      pp[c] = (float)mean;
      pp[4 + c] = (float)sqrt(var);
    }
    for (int j = 0; j < 3; ++j) {
      float m = fminf(sf[0][j], sf[1][j]);
      float M = fmaxf(sf[0][3 + j], sf[1][3 + j]);
      float q  = __fsub_rn(M, m);
      float A  = __fsub_rn(fs[j], q);
      float t1 = fmaxf(__fsub_rn(A, 0.001f), 0.0f);
      float t2 = fminf(__fadd_rn(A, 0.001f), 0.0f);
      float off = __fadd_rn(__fadd_rn(-m, __fmul_rn(t1, r1v[j])), __fmul_rn(t2, r2v[j]));
      pp[8 + j] = off;
      out_off[b * 3 + j] = off;
    }
  }
}

// Kernel C: per-point transform + all outputs.
// org (7 f32/point) is staged in LDS and streamed out as full float4 lines
// instead of 7 scalar stride-28B stores (≈7x L2 write-transaction amplification).
__global__ __launch_bounds__(256)
void k_main(const float4* __restrict__ pts, const int* __restrict__ tgt,
            const int* __restrict__ msk, const float* __restrict__ fs,
            const int* __restrict__ scale_p, AllRand ar,
            const float* __restrict__ params, float* __restrict__ out, int N) {
  const int b = blockIdx.y;
  const int i0 = blockIdx.x * 256;
  const int t = threadIdx.x;
  const int i = i0 + t;
  const bool active = (i < N);

  const SampleRand R = ar.r[b];
  const float* pp = params + b * 12;
  const float mean0 = pp[0], mean1 = pp[1], mean2 = pp[2], mean3 = pp[3];
  const float std0 = pp[4], std1 = pp[5], std2 = pp[6], std3 = pp[7];
  const float o0 = pp[8], o1 = pp[9], o2 = pp[10];
  const float fs0 = fs[0], fs1 = fs[1], fs2 = fs[2];
  const float sc = (float)(*scale_p);
  const size_t BN = (size_t)gridDim.y * (size_t)N;
  const size_t gi = (size_t)b * N + i;

  __shared__ __align__(16) float sorg[256 * 7];

  float X = 0.f, Y = 0.f, Z = 0.f;
  float f0 = 0.f, f1 = 0.f, f2 = 0.f, f3 = 0.f;

  if (active) {
    float4 P = pts[gi];
    float y = R.flipsign * P.y;
    float xr = __fsub_rn(__fmul_rn(P.x, R.c), __fmul_rn(y, R.s));
    float yr = __fadd_rn(__fmul_rn(P.x, R.s), __fmul_rn(y, R.c));
    X = __fadd_rn(xr, R.sx); Y = __fadd_rn(yr, R.sy); Z = __fadd_rn(P.z, R.sz);
    float W = P.w;
    f0 = __fsub_rn(X, mean0) / std0;
    f1 = __fsub_rn(Y, mean1) / std1;
    f2 = __fsub_rn(Z, mean2) / std2;
    f3 = __fsub_rn(W, mean3) / std3;
    float a0 = __fadd_rn(__fmul_rn(sc, X), o0);
    float a1 = __fadd_rn(__fmul_rn(sc, Y), o1);
    float a2 = __fadd_rn(__fmul_rn(sc, Z), o2);
    int m = msk[gi];
    bool valid = (fminf(fminf(a0, a1), a2) >= 0.0f) &&
                 (a0 < fs0) && (a1 < fs1) && (a2 < fs2) && (m > 0);
    int lx = valid ? (int)a0 : 0;
    int ly = valid ? (int)a1 : 0;
    int lz = valid ? (int)a2 : 0;

    float4* locs = (float4*)out;
    locs[gi] = make_float4((float)lx, (float)ly, (float)lz, (float)b);
    float4* feats = (float4*)(out + 4 * BN);
    feats[gi] = valid ? make_float4(f0, f1, f2, f3) : make_float4(0.f, 0.f, 0.f, 0.f);
    out[15 * BN + gi] = valid ? (float)tgt[gi] : 0.0f;
    out[16 * BN + gi] = (float)(m * (valid ? 1 : 0));
  }

  // stage org row into LDS (block-contiguous region of the org array)
  float* sr = sorg + t * 7;
  sr[0] = X; sr[1] = Y; sr[2] = Z;
  sr[3] = f0; sr[4] = f1; sr[5] = f2; sr[6] = f3;
  __syncthreads();

  const int cnt = min(256, N - i0);
  float* orgbase = out + 8 * BN + ((size_t)b * N + (size_t)i0) * 7;
  if (cnt == 256) {
    // 1792 floats = 448 float4, fully coalesced full-line stores
    const float4* s4 = (const float4*)sorg;
    float4* o4 = (float4*)orgbase;   // (b*N + i0)*7 and 8*BN are multiples of 4 -> 16B aligned
#pragma unroll
    for (int k = 0; k < 2; ++k) {
      int idx = t + k * 256;
      if (idx < 448) o4[idx] = s4[idx];
    }
  } else {
    const int total = cnt * 7;
    for (int k = t; k < total; k += 256) orgbase[k] = sorg[k];
  }
}

extern "C" void kernel_launch(void* const* d_in, const int* in_sizes, int n_in,
                              void* d_out, int out_size, void* d_ws, size_t ws_size,
                              hipStream_t stream) {
  const float4* pts = (const float4*)d_in[0];
  const int* tgt = (const int*)d_in[1];
  const int* msk = (const int*)d_in[2];
  const float* fs = (const float*)d_in[3];
  const int* scale_p = (const int*)d_in[4];
  float* out = (float*)d_out;

  const int B = B_FIXED;
  const int N = in_sizes[1] / B;
  const size_t BN = (size_t)B * (size_t)N;

  AllRand ar;
  fill_rand(ar);

  double* psum = (double*)d_ws;
  float* pmm = (float*)((char*)d_ws + (size_t)B * PB * 8 * sizeof(double));
  float* params = (float*)((char*)d_ws + (size_t)B * PB * 8 * sizeof(double)
                                       + (size_t)B * PB * 6 * sizeof(float));

  dim3 gA(PB, B);
  k_reduce<<<gA, 256, 0, stream>>>(pts, N, scale_p, ar, psum, pmm);
  k_params<<<B, PB, 0, stream>>>(psum, pmm, N, fs, ar, params, out + 17 * BN);
  dim3 gC((N + 255) / 256, B);
  k_main<<<gC, 256, 0, stream>>>(pts, tgt, msk, fs, scale_p, ar, params, out, N);
}